// Round 1
// baseline (19394.797 us; speedup 1.0000x reference)
//
#include <hip/hip_runtime.h>
#include <hip/hip_bf16.h>
#include <math.h>

#define T_STEPS 512
#define BATCH   64
#define INDIM   1024
#define HDIM    1024

using bf16x8 = __attribute__((ext_vector_type(8))) __bf16;
using f32x4  = __attribute__((ext_vector_type(4))) float;

struct WP {
    const float* wx[4];
    const float* wh[4];
    const float* bx[4];
    const float* bh[4];
};

// Pack 8 weight matrices into combined bf16 [4H][K] layouts + combined bias.
__global__ void pack_weights(WP p, __hip_bfloat16* __restrict__ Wx,
                             __hip_bfloat16* __restrict__ Wh, float* __restrict__ bias)
{
    int i = blockIdx.x * blockDim.x + threadIdx.x;
    const int stride = gridDim.x * blockDim.x;
    const int total = 4 * HDIM * INDIM;
    for (int idx = i; idx < total; idx += stride) {
        int g = idx >> 20;              // / (1024*1024)
        int r = idx & ((1 << 20) - 1);
        Wx[idx] = __float2bfloat16(p.wx[g][r]);
        Wh[idx] = __float2bfloat16(p.wh[g][r]);
    }
    if (i < 4 * HDIM) {
        int g = i >> 10, r = i & 1023;
        bias[i] = p.bx[g][r] + p.bh[g][r];
    }
}

__global__ void cast_f32_bf16(const float* __restrict__ in,
                              __hip_bfloat16* __restrict__ out, int n4)
{
    int i = blockIdx.x * blockDim.x + threadIdx.x;
    const int stride = gridDim.x * blockDim.x;
    for (; i < n4; i += stride) {
        float4 v = ((const float4*)in)[i];
        union { __hip_bfloat16 b[4]; short4 s; } u;
        u.b[0] = __float2bfloat16(v.x);
        u.b[1] = __float2bfloat16(v.y);
        u.b[2] = __float2bfloat16(v.z);
        u.b[3] = __float2bfloat16(v.w);
        ((short4*)out)[i] = u.s;
    }
}

__global__ void init_state(const float* __restrict__ H0, const float* __restrict__ C0,
                           __hip_bfloat16* __restrict__ h0, float* __restrict__ c)
{
    int i = blockIdx.x * blockDim.x + threadIdx.x;
    if (i < BATCH * HDIM) {
        h0[i] = __float2bfloat16(H0[i]);
        c[i]  = C0[i];
    }
}

__global__ void epilogue(const float* __restrict__ lasth, const float* __restrict__ c,
                         float* __restrict__ Hf, float* __restrict__ Cf)
{
    int i = blockIdx.x * blockDim.x + threadIdx.x;
    if (i < BATCH * HDIM) {
        Hf[i] = lasth[i];
        Cf[i] = c[i];
    }
}

// One LSTM timestep: g = x[t]@Wx^T + h@Wh^T + bias, fused gates.
// Grid: 64 WGs (16 hidden cols each). Block: 1024 threads = 16 waves =
// 4 gates x 4 K-quarters. MFMA 16x16x32 bf16, M=batch=64 (4 frags), N=16.
__global__ __launch_bounds__(1024, 1) void lstm_step(
    const __hip_bfloat16* __restrict__ xb,     // [B][IN] for this t
    const __hip_bfloat16* __restrict__ Wx,     // [4H][IN] bf16
    const __hip_bfloat16* __restrict__ Wh,     // [4H][H]  bf16
    const float* __restrict__ bias,            // [4H]
    const __hip_bfloat16* __restrict__ h_in,   // [B][H]
    __hip_bfloat16* __restrict__ h_out,        // [B][H]
    float* __restrict__ cbuf,                  // [B][H]
    float* __restrict__ outh)                  // [B][H] f32 (out[t])
{
    __shared__ float gl[16][BATCH][16];        // 64 KiB: per-wave partial g

    const int tid  = threadIdx.x;
    const int w    = tid >> 6;       // wave 0..15
    const int lane = tid & 63;
    const int gt   = w >> 2;         // gate 0..3 (i,f,o,c)
    const int kq   = w & 3;          // K quarter
    const int j0   = blockIdx.x << 4;
    const int rA   = lane & 15;      // A row within tile / B col
    const int kg   = (lane >> 4) << 3;

    f32x4 acc[4] = {};
    const int n0 = gt * HDIM + j0;

    // x-projection part: K over INDIM quarter
    {
        const __hip_bfloat16* Wrow = Wx + (size_t)(n0 + rA) * INDIM;
        const __hip_bfloat16* Arow = xb + (size_t)rA * INDIM;
#pragma unroll
        for (int kk = 0; kk < 8; ++kk) {
            const int kb = (kq << 8) + (kk << 5) + kg;
            bf16x8 bf = *reinterpret_cast<const bf16x8*>(Wrow + kb);
#pragma unroll
            for (int m = 0; m < 4; ++m) {
                bf16x8 af = *reinterpret_cast<const bf16x8*>(Arow + (m << 4) * INDIM + kb);
                acc[m] = __builtin_amdgcn_mfma_f32_16x16x32_bf16(af, bf, acc[m], 0, 0, 0);
            }
        }
    }
    // recurrent part: K over HDIM quarter
    {
        const __hip_bfloat16* Wrow = Wh + (size_t)(n0 + rA) * HDIM;
        const __hip_bfloat16* Arow = h_in + (size_t)rA * HDIM;
#pragma unroll
        for (int kk = 0; kk < 8; ++kk) {
            const int kb = (kq << 8) + (kk << 5) + kg;
            bf16x8 bf = *reinterpret_cast<const bf16x8*>(Wrow + kb);
#pragma unroll
            for (int m = 0; m < 4; ++m) {
                bf16x8 af = *reinterpret_cast<const bf16x8*>(Arow + (m << 4) * INDIM + kb);
                acc[m] = __builtin_amdgcn_mfma_f32_16x16x32_bf16(af, bf, acc[m], 0, 0, 0);
            }
        }
    }

    // write per-wave partials: C/D layout col=lane&15, row=(lane>>4)*4+r
#pragma unroll
    for (int m = 0; m < 4; ++m) {
        const int bb = (m << 4) + ((lane >> 4) << 2);
#pragma unroll
        for (int r = 0; r < 4; ++r)
            gl[w][bb + r][rA] = acc[m][r];
    }
    __syncthreads();

    // gate phase: one thread per (b, jj)
    const int b  = tid >> 4;
    const int jj = tid & 15;
    float gi = gl[0][b][jj] + gl[1][b][jj] + gl[2][b][jj]  + gl[3][b][jj]  + bias[0 * HDIM + j0 + jj];
    float gf = gl[4][b][jj] + gl[5][b][jj] + gl[6][b][jj]  + gl[7][b][jj]  + bias[1 * HDIM + j0 + jj];
    float go = gl[8][b][jj] + gl[9][b][jj] + gl[10][b][jj] + gl[11][b][jj] + bias[2 * HDIM + j0 + jj];
    float gc = gl[12][b][jj]+ gl[13][b][jj]+ gl[14][b][jj] + gl[15][b][jj] + bias[3 * HDIM + j0 + jj];

    const int idx = b * HDIM + j0 + jj;
    const float cold = cbuf[idx];
    const float i_ = 1.f / (1.f + __expf(-gi));
    const float f_ = 1.f / (1.f + __expf(-gf));
    const float o_ = 1.f / (1.f + __expf(-go));
    const float ct = tanhf(gc);
    const float cn = f_ * cold + i_ * ct;
    const float hn = o_ * tanhf(cn);
    cbuf[idx] = cn;
    outh[idx] = hn;
    h_out[idx] = __float2bfloat16(hn);
}

extern "C" void kernel_launch(void* const* d_in, const int* in_sizes, int n_in,
                              void* d_out, int out_size, void* d_ws, size_t ws_size,
                              hipStream_t stream)
{
    const float* inputs = (const float*)d_in[0];
    const float* H0     = (const float*)d_in[1];
    const float* C0     = (const float*)d_in[2];

    WP wp;
    // dict order: Wix,bix,Wih,bih,Wfx,bfx,Wfh,bfh,Wox,box,Woh,boh,Wcx,bcx,Wch,bch
    wp.wx[0] = (const float*)d_in[3];  wp.bx[0] = (const float*)d_in[4];
    wp.wh[0] = (const float*)d_in[5];  wp.bh[0] = (const float*)d_in[6];
    wp.wx[1] = (const float*)d_in[7];  wp.bx[1] = (const float*)d_in[8];
    wp.wh[1] = (const float*)d_in[9];  wp.bh[1] = (const float*)d_in[10];
    wp.wx[2] = (const float*)d_in[11]; wp.bx[2] = (const float*)d_in[12];
    wp.wh[2] = (const float*)d_in[13]; wp.bh[2] = (const float*)d_in[14];
    wp.wx[3] = (const float*)d_in[15]; wp.bx[3] = (const float*)d_in[16];
    wp.wh[3] = (const float*)d_in[17]; wp.bh[3] = (const float*)d_in[18];

    char* ws = (char*)d_ws;
    size_t off = 0;
    auto alloc = [&](size_t bytes) {
        void* p = ws + off;
        off = (off + bytes + 255) & ~(size_t)255;
        return p;
    };
    __hip_bfloat16* Wx   = (__hip_bfloat16*)alloc((size_t)4 * HDIM * INDIM * 2);
    __hip_bfloat16* Wh   = (__hip_bfloat16*)alloc((size_t)4 * HDIM * HDIM * 2);
    float*          bias = (float*)alloc((size_t)4 * HDIM * 4);
    __hip_bfloat16* xb   = (__hip_bfloat16*)alloc((size_t)T_STEPS * BATCH * INDIM * 2);
    __hip_bfloat16* hb0  = (__hip_bfloat16*)alloc((size_t)BATCH * HDIM * 2);
    __hip_bfloat16* hb1  = (__hip_bfloat16*)alloc((size_t)BATCH * HDIM * 2);
    float*          cbuf = (float*)alloc((size_t)BATCH * HDIM * 4);
    if (off > ws_size) return;  // workspace too small: fail loudly via validation

    float* out = (float*)d_out;

    hipLaunchKernelGGL(pack_weights, dim3(2048), dim3(256), 0, stream, wp, Wx, Wh, bias);
    hipLaunchKernelGGL(cast_f32_bf16, dim3(2048), dim3(256), 0, stream,
                       inputs, xb, T_STEPS * BATCH * INDIM / 4);
    hipLaunchKernelGGL(init_state, dim3(256), dim3(256), 0, stream, H0, C0, hb0, cbuf);

    __hip_bfloat16* hbuf[2] = { hb0, hb1 };
    for (int t = 0; t < T_STEPS; ++t) {
        hipLaunchKernelGGL(lstm_step, dim3(64), dim3(1024), 0, stream,
                           xb + (size_t)t * BATCH * INDIM, Wx, Wh, bias,
                           hbuf[t & 1], hbuf[(t + 1) & 1], cbuf,
                           out + (size_t)t * BATCH * HDIM);
    }
    hipLaunchKernelGGL(epilogue, dim3(256), dim3(256), 0, stream,
                       out + (size_t)(T_STEPS - 1) * BATCH * HDIM, cbuf,
                       out + (size_t)T_STEPS * BATCH * HDIM,
                       out + (size_t)T_STEPS * BATCH * HDIM + BATCH * HDIM);
}

// Round 3
// 9980.830 us; speedup vs baseline: 1.9432x; 1.9432x over previous
//
#include <hip/hip_runtime.h>
#include <hip/hip_bf16.h>
#include <math.h>

#define T_STEPS 512
#define BATCH   64
#define INDIM   1024
#define HDIM    1024
#define NWG     128      // persistent WGs; each owns 8 hidden cols

using bf16x8 = __attribute__((ext_vector_type(8))) __bf16;
using f32x4  = __attribute__((ext_vector_type(4))) float;
using sht8   = __attribute__((ext_vector_type(8))) short;

struct WP {
    const float* wx[4];
    const float* wh[4];
    const float* bx[4];
    const float* bh[4];
};

// Pack 8 weight matrices into combined bf16 [4H][K] layouts + combined bias.
__global__ void pack_weights(WP p, __hip_bfloat16* __restrict__ Wx,
                             __hip_bfloat16* __restrict__ Wh, float* __restrict__ bias)
{
    int i = blockIdx.x * blockDim.x + threadIdx.x;
    const int stride = gridDim.x * blockDim.x;
    const int total = 4 * HDIM * INDIM;
    for (int idx = i; idx < total; idx += stride) {
        int g = idx >> 20;
        int r = idx & ((1 << 20) - 1);
        Wx[idx] = __float2bfloat16(p.wx[g][r]);
        Wh[idx] = __float2bfloat16(p.wh[g][r]);
    }
    if (i < 4 * HDIM) {
        int g = i >> 10, r = i & 1023;
        bias[i] = p.bx[g][r] + p.bh[g][r];
    }
}

__global__ void cast_f32_bf16(const float* __restrict__ in,
                              __hip_bfloat16* __restrict__ out, int n4)
{
    int i = blockIdx.x * blockDim.x + threadIdx.x;
    const int stride = gridDim.x * blockDim.x;
    for (; i < n4; i += stride) {
        float4 v = ((const float4*)in)[i];
        union { __hip_bfloat16 b[4]; short4 s; } u;
        u.b[0] = __float2bfloat16(v.x);
        u.b[1] = __float2bfloat16(v.y);
        u.b[2] = __float2bfloat16(v.z);
        u.b[3] = __float2bfloat16(v.w);
        ((short4*)out)[i] = u.s;
    }
}

__global__ void init_state(const float* __restrict__ H0, const float* __restrict__ C0,
                           __hip_bfloat16* __restrict__ h0, float* __restrict__ c)
{
    int i = blockIdx.x * blockDim.x + threadIdx.x;
    if (i < BATCH * HDIM) {
        h0[i] = __float2bfloat16(H0[i]);
        c[i]  = C0[i];
    }
}

__global__ void epilogue(const float* __restrict__ lasth, const float* __restrict__ c,
                         float* __restrict__ Hf, float* __restrict__ Cf)
{
    int i = blockIdx.x * blockDim.x + threadIdx.x;
    if (i < BATCH * HDIM) {
        Hf[i] = lasth[i];
        Cf[i] = c[i];
    }
}

// xproj GEMM: xp[t][n][b] = sum_k xb[t*64+b][k] * Wx[n][k]   (f32 out)
// Grid (TC, 32). Per WG: one t (M=64), N=128. 4 waves, each 2 n-tiles of 16.
__global__ __launch_bounds__(256, 2) void xproj_gemm(
    const __hip_bfloat16* __restrict__ xb,   // chunk base [TC*64][1024]
    const __hip_bfloat16* __restrict__ Wx,   // [4096][1024]
    float* __restrict__ xp)                  // [TC][4096][64]
{
    __shared__ float ct[4][64][33];
    const int t = blockIdx.x;
    const int n0 = blockIdx.y << 7;
    const int tid = threadIdx.x, w = tid >> 6, lane = tid & 63;
    const int rA = lane & 15, kg = (lane >> 4) << 3;
    const int nw = n0 + (w << 5);
    f32x4 acc[2][4] = {};
    const __hip_bfloat16* Arow = xb + (((size_t)t << 6) + rA) * 1024 + kg;
    const __hip_bfloat16* Brow = Wx + ((size_t)(nw + rA) << 10) + kg;
#pragma unroll 4
    for (int kk = 0; kk < 32; ++kk) {
        const int kb = kk << 5;
        bf16x8 bf0 = *reinterpret_cast<const bf16x8*>(Brow + kb);
        bf16x8 bf1 = *reinterpret_cast<const bf16x8*>(Brow + (16 << 10) + kb);
        bf16x8 af[4];
#pragma unroll
        for (int m = 0; m < 4; ++m)
            af[m] = *reinterpret_cast<const bf16x8*>(Arow + (m << 14) + kb);
#pragma unroll
        for (int m = 0; m < 4; ++m) {
            acc[0][m] = __builtin_amdgcn_mfma_f32_16x16x32_bf16(af[m], bf0, acc[0][m], 0, 0, 0);
            acc[1][m] = __builtin_amdgcn_mfma_f32_16x16x32_bf16(af[m], bf1, acc[1][m], 0, 0, 0);
        }
    }
#pragma unroll
    for (int n2 = 0; n2 < 2; ++n2)
#pragma unroll
        for (int m = 0; m < 4; ++m) {
            const int bb = (m << 4) + ((lane >> 4) << 2);
#pragma unroll
            for (int r = 0; r < 4; ++r)
                ct[w][bb + r][(n2 << 4) + rA] = acc[n2][m][r];
        }
    __syncthreads();
    const int n = lane & 31, mh = lane >> 5;
    float* obase = xp + ((size_t)t * 4096 + nw + n) * 64 + (mh << 5);
#pragma unroll
    for (int j = 0; j < 8; ++j) {
        const int m0 = (mh << 5) + (j << 2);
        *reinterpret_cast<float4*>(obase + (j << 2)) = make_float4(
            ct[w][m0 + 0][n], ct[w][m0 + 1][n], ct[w][m0 + 2][n], ct[w][m0 + 3][n]);
    }
}

// Manual device-scope grid barrier (graph-capture safe, no cooperative launch).
// All 128 WGs are co-resident (128 <= 256 CUs, 1 block/CU resources).
__device__ __forceinline__ void gbar(unsigned* bar, unsigned target)
{
    __syncthreads();
    if (threadIdx.x == 0) {
        __threadfence();                       // release this WG's global writes
        atomicAdd(bar, 1u);                    // device-scope by default
        while (__hip_atomic_load(bar, __ATOMIC_RELAXED, __HIP_MEMORY_SCOPE_AGENT) < target)
            __builtin_amdgcn_s_sleep(1);
        __threadfence();                       // acquire other WGs' writes
    }
    __syncthreads();
}

// Persistent recurrence kernel. Grid = NWG(128) x 256 threads.
// WG wg owns hidden cols [wg*8, wg*8+8): 32 gate-rows, Wh slice in registers.
// Per step: h-GEMM (K split across 4 waves), LDS reduce, fused gates, stores,
// one global barrier. h double-buffered; c/bias persistent in registers.
__global__ __launch_bounds__(256, 1) void lstm_persist(
    const float* __restrict__ xp,            // [TC][4096][64]
    const __hip_bfloat16* __restrict__ Wh,   // [4096][1024]
    const float* __restrict__ bias,          // [4096]
    __hip_bfloat16* __restrict__ hA,         // state at chunk start
    __hip_bfloat16* __restrict__ hB,
    float* __restrict__ cbuf,                // [64][1024]
    float* __restrict__ out,                 // [TC][64][1024]
    unsigned* __restrict__ bar,              // global barrier counter
    unsigned barBase,                        // barrier count consumed so far
    int TC)
{
    __shared__ float gl[4][64][33];          // per-wave partials [w][b][r<32]
    __shared__ float hs[64][9];              // gathered h f32 (padded)

    const int tid  = threadIdx.x;
    const int w    = tid >> 6;
    const int lane = tid & 63;
    const int rA   = lane & 15;
    const int kg   = (lane >> 4) << 3;
    const int j0   = blockIdx.x << 3;

    // Preload this wave's Wh fragments (its K-quarter of 32 gate-rows).
    // gate-row r -> global row (r>>3)*1024 + j0 + (r&7)
    bf16x8 whf[2][8];
#pragma unroll
    for (int n2 = 0; n2 < 2; ++n2) {
        const int row  = (n2 << 4) + rA;
        const int grow = ((row >> 3) << 10) + j0 + (row & 7);
        const __hip_bfloat16* wr = Wh + ((size_t)grow << 10) + (w << 8) + kg;
#pragma unroll
        for (int kk = 0; kk < 8; ++kk)
            whf[n2][kk] = *reinterpret_cast<const bf16x8*>(wr + (kk << 5));
    }

    // Gate-phase persistent state: thread (b=lane, cols cl=w*2+{0,1})
    const int b = lane;
    float creg[2], brg[2][4];
#pragma unroll
    for (int e = 0; e < 2; ++e) {
        const int cl = (w << 1) + e;
        creg[e] = cbuf[(b << 10) + j0 + cl];
#pragma unroll
        for (int g = 0; g < 4; ++g) brg[e][g] = bias[(g << 10) + j0 + cl];
    }

    for (int s = 0; s < TC; ++s) {
        const __hip_bfloat16* hp = (s & 1) ? hB : hA;
        __hip_bfloat16*       hn = (s & 1) ? hA : hB;

        // Prefetch xproj for this step (HBM latency hides under MFMA).
        const float* xpt = xp + (size_t)s * 262144;
        float xv[2][4];
#pragma unroll
        for (int e = 0; e < 2; ++e)
#pragma unroll
            for (int g = 0; g < 4; ++g)
                xv[e][g] = xpt[(((g << 10) + j0 + (w << 1) + e) << 6) + b];

        // h-GEMM: this wave's K-quarter
        f32x4 acc[2][4] = {};
        const __hip_bfloat16* hbase = hp + (w << 8) + kg;
#pragma unroll
        for (int kk = 0; kk < 8; ++kk) {
            bf16x8 af[4];
#pragma unroll
            for (int m = 0; m < 4; ++m)
                af[m] = *reinterpret_cast<const bf16x8*>(
                    hbase + (((size_t)(m << 4) + rA) << 10) + (kk << 5));
#pragma unroll
            for (int n2 = 0; n2 < 2; ++n2)
#pragma unroll
                for (int m = 0; m < 4; ++m)
                    acc[n2][m] = __builtin_amdgcn_mfma_f32_16x16x32_bf16(
                        af[m], whf[n2][kk], acc[n2][m], 0, 0, 0);
        }

        // Write partials: C/D layout col=lane&15, row=(lane>>4)*4+r
#pragma unroll
        for (int n2 = 0; n2 < 2; ++n2)
#pragma unroll
            for (int m = 0; m < 4; ++m) {
                const int bb = (m << 4) + ((lane >> 4) << 2);
#pragma unroll
                for (int r = 0; r < 4; ++r)
                    gl[w][bb + r][(n2 << 4) + rA] = acc[n2][m][r];
            }
        __syncthreads();

        // Fused gates: thread handles (b, cl=w*2+e); r-index = g*8+cl
#pragma unroll
        for (int e = 0; e < 2; ++e) {
            const int cl = (w << 1) + e;
            float gv[4];
#pragma unroll
            for (int g = 0; g < 4; ++g)
                gv[g] = gl[0][b][(g << 3) + cl] + gl[1][b][(g << 3) + cl]
                      + gl[2][b][(g << 3) + cl] + gl[3][b][(g << 3) + cl]
                      + brg[e][g] + xv[e][g];
            const float i_ = 1.f / (1.f + __expf(-gv[0]));
            const float f_ = 1.f / (1.f + __expf(-gv[1]));
            const float o_ = 1.f / (1.f + __expf(-gv[2]));
            const float ct = tanhf(gv[3]);
            const float cn = f_ * creg[e] + i_ * ct;
            creg[e] = cn;
            hs[b][cl] = o_ * tanhf(cn);
        }
        __syncthreads();

        // Gathered stores: one row per thread (tid<64): 32B out + 16B h bf16
        if (tid < 64) {
            float v[8];
#pragma unroll
            for (int k = 0; k < 8; ++k) v[k] = hs[tid][k];
            float* orow = out + (((size_t)s << 6) + tid) * 1024 + j0;
            *reinterpret_cast<float4*>(orow)     = make_float4(v[0], v[1], v[2], v[3]);
            *reinterpret_cast<float4*>(orow + 4) = make_float4(v[4], v[5], v[6], v[7]);
            union { __hip_bfloat16 bh[8]; sht8 sv; } u;
#pragma unroll
            for (int k = 0; k < 8; ++k) u.bh[k] = __float2bfloat16(v[k]);
            *reinterpret_cast<sht8*>(hn + ((size_t)tid << 10) + j0) = u.sv;
        }
        gbar(bar, barBase + (unsigned)(s + 1) * NWG);
    }

    // Persist c for next chunk / final epilogue
#pragma unroll
    for (int e = 0; e < 2; ++e)
        cbuf[(b << 10) + j0 + (w << 1) + e] = creg[e];
}

extern "C" void kernel_launch(void* const* d_in, const int* in_sizes, int n_in,
                              void* d_out, int out_size, void* d_ws, size_t ws_size,
                              hipStream_t stream)
{
    const float* inputs = (const float*)d_in[0];
    const float* H0     = (const float*)d_in[1];
    const float* C0     = (const float*)d_in[2];

    WP wp;
    wp.wx[0] = (const float*)d_in[3];  wp.bx[0] = (const float*)d_in[4];
    wp.wh[0] = (const float*)d_in[5];  wp.bh[0] = (const float*)d_in[6];
    wp.wx[1] = (const float*)d_in[7];  wp.bx[1] = (const float*)d_in[8];
    wp.wh[1] = (const float*)d_in[9];  wp.bh[1] = (const float*)d_in[10];
    wp.wx[2] = (const float*)d_in[11]; wp.bx[2] = (const float*)d_in[12];
    wp.wh[2] = (const float*)d_in[13]; wp.bh[2] = (const float*)d_in[14];
    wp.wx[3] = (const float*)d_in[15]; wp.bx[3] = (const float*)d_in[16];
    wp.wh[3] = (const float*)d_in[17]; wp.bh[3] = (const float*)d_in[18];

    char* ws = (char*)d_ws;
    size_t off = 0;
    auto alloc = [&](size_t bytes) {
        void* p = ws + off;
        off = (off + bytes + 255) & ~(size_t)255;
        return p;
    };
    __hip_bfloat16* Wx   = (__hip_bfloat16*)alloc((size_t)4 * HDIM * INDIM * 2);
    __hip_bfloat16* Wh   = (__hip_bfloat16*)alloc((size_t)4 * HDIM * HDIM * 2);
    float*          bias = (float*)alloc((size_t)4 * HDIM * 4);
    __hip_bfloat16* xb   = (__hip_bfloat16*)alloc((size_t)T_STEPS * BATCH * INDIM * 2);
    __hip_bfloat16* hb0  = (__hip_bfloat16*)alloc((size_t)BATCH * HDIM * 2);
    __hip_bfloat16* hb1  = (__hip_bfloat16*)alloc((size_t)BATCH * HDIM * 2);
    float*          cbuf = (float*)alloc((size_t)BATCH * HDIM * 4);
    unsigned*       bar  = (unsigned*)alloc(256);

    // xproj chunk buffer: 1 MB per timestep ([4H][B] f32). Pick largest chunk
    // (divisor of 512) that fits the remaining workspace.
    const size_t per_t = (size_t)4 * HDIM * BATCH * 4;
    int TC = 0;
    for (int tc : {512, 256, 128, 64, 32, 16})
        if (off + (size_t)tc * per_t <= ws_size) { TC = tc; break; }
    if (TC == 0) return;
    float* xp = (float*)alloc((size_t)TC * per_t);

    float* out = (float*)d_out;

    hipMemsetAsync(bar, 0, 4, stream);       // deterministic across replays
    hipLaunchKernelGGL(pack_weights, dim3(2048), dim3(256), 0, stream, wp, Wx, Wh, bias);
    hipLaunchKernelGGL(cast_f32_bf16, dim3(2048), dim3(256), 0, stream,
                       inputs, xb, T_STEPS * BATCH * INDIM / 4);
    hipLaunchKernelGGL(init_state, dim3(256), dim3(256), 0, stream, H0, C0, hb0, cbuf);

    unsigned barBase = 0;
    for (int t0 = 0; t0 < T_STEPS; t0 += TC) {
        hipLaunchKernelGGL(xproj_gemm, dim3(TC, 32), dim3(256), 0, stream,
                           xb + (size_t)t0 * BATCH * INDIM, Wx, xp);
        hipLaunchKernelGGL(lstm_persist, dim3(NWG), dim3(256), 0, stream,
                           (const float*)xp, (const __hip_bfloat16*)Wh,
                           (const float*)bias, hb0, hb1, cbuf,
                           out + (size_t)t0 * BATCH * HDIM, bar, barBase, TC);
        barBase += (unsigned)TC * NWG;
    }
    hipLaunchKernelGGL(epilogue, dim3(256), dim3(256), 0, stream,
                       out + (size_t)(T_STEPS - 1) * BATCH * HDIM, cbuf,
                       out + (size_t)T_STEPS * BATCH * HDIM,
                       out + (size_t)T_STEPS * BATCH * HDIM + BATCH * HDIM);
}

// Round 5
// 9295.700 us; speedup vs baseline: 2.0864x; 1.0737x over previous
//
#include <hip/hip_runtime.h>
#include <hip/hip_bf16.h>
#include <math.h>

#define T_STEPS 512
#define BATCH   64
#define INDIM   1024
#define HDIM    1024
#define NWG     128      // persistent WGs; each owns 8 hidden cols

using bf16x8 = __attribute__((ext_vector_type(8))) __bf16;
using f32x4  = __attribute__((ext_vector_type(4))) float;
using sht8   = __attribute__((ext_vector_type(8))) short;

struct WP {
    const float* wx[4];
    const float* wh[4];
    const float* bx[4];
    const float* bh[4];
};

// Pack 8 weight matrices into combined bf16 [4H][K] layouts + combined bias.
__global__ void pack_weights(WP p, __hip_bfloat16* __restrict__ Wx,
                             __hip_bfloat16* __restrict__ Wh, float* __restrict__ bias)
{
    int i = blockIdx.x * blockDim.x + threadIdx.x;
    const int stride = gridDim.x * blockDim.x;
    const int total = 4 * HDIM * INDIM;
    for (int idx = i; idx < total; idx += stride) {
        int g = idx >> 20;
        int r = idx & ((1 << 20) - 1);
        Wx[idx] = __float2bfloat16(p.wx[g][r]);
        Wh[idx] = __float2bfloat16(p.wh[g][r]);
    }
    if (i < 4 * HDIM) {
        int g = i >> 10, r = i & 1023;
        bias[i] = p.bx[g][r] + p.bh[g][r];
    }
}

__global__ void cast_f32_bf16(const float* __restrict__ in,
                              __hip_bfloat16* __restrict__ out, int n4)
{
    int i = blockIdx.x * blockDim.x + threadIdx.x;
    const int stride = gridDim.x * blockDim.x;
    for (; i < n4; i += stride) {
        float4 v = ((const float4*)in)[i];
        union { __hip_bfloat16 b[4]; short4 s; } u;
        u.b[0] = __float2bfloat16(v.x);
        u.b[1] = __float2bfloat16(v.y);
        u.b[2] = __float2bfloat16(v.z);
        u.b[3] = __float2bfloat16(v.w);
        ((short4*)out)[i] = u.s;
    }
}

__global__ void init_state(const float* __restrict__ H0, const float* __restrict__ C0,
                           __hip_bfloat16* __restrict__ h0, float* __restrict__ c)
{
    int i = blockIdx.x * blockDim.x + threadIdx.x;
    if (i < BATCH * HDIM) {
        h0[i] = __float2bfloat16(H0[i]);
        c[i]  = C0[i];
    }
}

__global__ void epilogue(const float* __restrict__ lasth, const float* __restrict__ c,
                         float* __restrict__ Hf, float* __restrict__ Cf)
{
    int i = blockIdx.x * blockDim.x + threadIdx.x;
    if (i < BATCH * HDIM) {
        Hf[i] = lasth[i];
        Cf[i] = c[i];
    }
}

// xproj GEMM: xp[t][n][b] = sum_k xb[t*64+b][k] * Wx[n][k]   (f32 out)
// Grid (TC, 32). Per WG: one t (M=64), N=128. 4 waves, each 2 n-tiles of 16.
__global__ __launch_bounds__(256, 2) void xproj_gemm(
    const __hip_bfloat16* __restrict__ xb,   // chunk base [TC*64][1024]
    const __hip_bfloat16* __restrict__ Wx,   // [4096][1024]
    float* __restrict__ xp)                  // [TC][4096][64]
{
    __shared__ float ct[4][64][33];
    const int t = blockIdx.x;
    const int n0 = blockIdx.y << 7;
    const int tid = threadIdx.x, w = tid >> 6, lane = tid & 63;
    const int rA = lane & 15, kg = (lane >> 4) << 3;
    const int nw = n0 + (w << 5);
    f32x4 acc[2][4] = {};
    const __hip_bfloat16* Arow = xb + (((size_t)t << 6) + rA) * 1024 + kg;
    const __hip_bfloat16* Brow = Wx + ((size_t)(nw + rA) << 10) + kg;
#pragma unroll 4
    for (int kk = 0; kk < 32; ++kk) {
        const int kb = kk << 5;
        bf16x8 bf0 = *reinterpret_cast<const bf16x8*>(Brow + kb);
        bf16x8 bf1 = *reinterpret_cast<const bf16x8*>(Brow + (16 << 10) + kb);
        bf16x8 af[4];
#pragma unroll
        for (int m = 0; m < 4; ++m)
            af[m] = *reinterpret_cast<const bf16x8*>(Arow + (m << 14) + kb);
#pragma unroll
        for (int m = 0; m < 4; ++m) {
            acc[0][m] = __builtin_amdgcn_mfma_f32_16x16x32_bf16(af[m], bf0, acc[0][m], 0, 0, 0);
            acc[1][m] = __builtin_amdgcn_mfma_f32_16x16x32_bf16(af[m], bf1, acc[1][m], 0, 0, 0);
        }
    }
#pragma unroll
    for (int n2 = 0; n2 < 2; ++n2)
#pragma unroll
        for (int m = 0; m < 4; ++m) {
            const int bb = (m << 4) + ((lane >> 4) << 2);
#pragma unroll
            for (int r = 0; r < 4; ++r)
                ct[w][bb + r][(n2 << 4) + rA] = acc[n2][m][r];
        }
    __syncthreads();
    const int n = lane & 31, mh = lane >> 5;
    float* obase = xp + ((size_t)t * 4096 + nw + n) * 64 + (mh << 5);
#pragma unroll
    for (int j = 0; j < 8; ++j) {
        const int m0 = (mh << 5) + (j << 2);
        *reinterpret_cast<float4*>(obase + (j << 2)) = make_float4(
            ct[w][m0 + 0][n], ct[w][m0 + 1][n], ct[w][m0 + 2][n], ct[w][m0 + 3][n]);
    }
}

// Distributed-flag global barrier (graph-capture safe, no contended RMW).
// flags[wg*16]: monotonically increasing step count per WG (64B stride).
// Release/acquire semantics identical to R3's HW-validated gbar.
// Spin is gentle: only wave 0 polls (2 flags/lane) with s_sleep between
// polls, so the 128 release-stores can always land (no L2 starvation).
__device__ __forceinline__ void gbar_flags(unsigned* flags, unsigned target)
{
    __syncthreads();                         // per-wave vmcnt(0): h stores at L2
    if (threadIdx.x == 0) {
        __threadfence();                     // L2 writeback: visible device-wide
        __hip_atomic_store(&flags[(int)blockIdx.x * 16], target,
                           __ATOMIC_RELEASE, __HIP_MEMORY_SCOPE_AGENT);
    }
    if (threadIdx.x < 64) {
        const unsigned* f0 = &flags[threadIdx.x * 16];
        const unsigned* f1 = &flags[(threadIdx.x + 64) * 16];
        while (__hip_atomic_load(f0, __ATOMIC_RELAXED, __HIP_MEMORY_SCOPE_AGENT) < target ||
               __hip_atomic_load(f1, __ATOMIC_RELAXED, __HIP_MEMORY_SCOPE_AGENT) < target)
            __builtin_amdgcn_s_sleep(2);
    }
    __syncthreads();
    if (threadIdx.x == 0) __threadfence();   // acquire: invalidate before reading h
    __syncthreads();
}

// Persistent recurrence kernel. Grid = NWG(128) x 256 threads.
// WG wg owns hidden cols [wg*8, wg*8+8): 32 gate-rows, Wh slice in registers.
// Per step: h-GEMM (K split across 4 waves), LDS reduce, fused gates, stores,
// one global barrier. h double-buffered; c/bias persistent in registers.
// xproj reads are software-pipelined one step ahead.
__global__ __launch_bounds__(256, 1) void lstm_persist(
    const float* __restrict__ xp,            // [TC][4096][64]
    const __hip_bfloat16* __restrict__ Wh,   // [4096][1024]
    const float* __restrict__ bias,          // [4096]
    __hip_bfloat16* __restrict__ hA,         // state at chunk start
    __hip_bfloat16* __restrict__ hB,
    float* __restrict__ cbuf,                // [64][1024]
    float* __restrict__ out,                 // [TC][64][1024]
    unsigned* __restrict__ flags,            // [NWG*16] barrier flags
    unsigned stepBase,                       // steps completed in prior chunks
    int TC)
{
    __shared__ float gl[4][64][33];          // per-wave partials [w][b][r<32]
    __shared__ float hs[64][9];              // gathered h f32 (padded)

    const int tid  = threadIdx.x;
    const int w    = tid >> 6;
    const int lane = tid & 63;
    const int rA   = lane & 15;
    const int kg   = (lane >> 4) << 3;
    const int j0   = blockIdx.x << 3;

    // Preload this wave's Wh fragments (its K-quarter of 32 gate-rows).
    // gate-row r -> global row (r>>3)*1024 + j0 + (r&7)
    bf16x8 whf[2][8];
#pragma unroll
    for (int n2 = 0; n2 < 2; ++n2) {
        const int row  = (n2 << 4) + rA;
        const int grow = ((row >> 3) << 10) + j0 + (row & 7);
        const __hip_bfloat16* wr = Wh + ((size_t)grow << 10) + (w << 8) + kg;
#pragma unroll
        for (int kk = 0; kk < 8; ++kk)
            whf[n2][kk] = *reinterpret_cast<const bf16x8*>(wr + (kk << 5));
    }

    // Gate-phase persistent state: thread (b=lane, cols cl=w*2+{0,1})
    const int b = lane;
    float creg[2], brg[2][4];
#pragma unroll
    for (int e = 0; e < 2; ++e) {
        const int cl = (w << 1) + e;
        creg[e] = cbuf[(b << 10) + j0 + cl];
#pragma unroll
        for (int g = 0; g < 4; ++g) brg[e][g] = bias[(g << 10) + j0 + cl];
    }

#define LOAD_XV(dst, sidx)                                                     \
    do {                                                                       \
        const float* xpt_ = xp + (size_t)(sidx) * 262144;                      \
        _Pragma("unroll") for (int e = 0; e < 2; ++e)                          \
        _Pragma("unroll") for (int g = 0; g < 4; ++g)                          \
            dst[e][g] = xpt_[(((g << 10) + j0 + (w << 1) + e) << 6) + b];      \
    } while (0)

    float xv[2][4];
    LOAD_XV(xv, 0);

    for (int s = 0; s < TC; ++s) {
        const __hip_bfloat16* hp = (s & 1) ? hB : hA;
        __hip_bfloat16*       hn = (s & 1) ? hA : hB;

        // Prefetch next step's xproj early; latency hides under GEMM+gates+barrier.
        float xn[2][4];
        if (s + 1 < TC) LOAD_XV(xn, s + 1);

        // h-GEMM: this wave's K-quarter
        f32x4 acc[2][4] = {};
        const __hip_bfloat16* hbase = hp + (w << 8) + kg;
#pragma unroll
        for (int kk = 0; kk < 8; ++kk) {
            bf16x8 af[4];
#pragma unroll
            for (int m = 0; m < 4; ++m)
                af[m] = *reinterpret_cast<const bf16x8*>(
                    hbase + (((size_t)(m << 4) + rA) << 10) + (kk << 5));
#pragma unroll
            for (int n2 = 0; n2 < 2; ++n2)
#pragma unroll
                for (int m = 0; m < 4; ++m)
                    acc[n2][m] = __builtin_amdgcn_mfma_f32_16x16x32_bf16(
                        af[m], whf[n2][kk], acc[n2][m], 0, 0, 0);
        }

        // Write partials: C/D layout col=lane&15, row=(lane>>4)*4+r
#pragma unroll
        for (int n2 = 0; n2 < 2; ++n2)
#pragma unroll
            for (int m = 0; m < 4; ++m) {
                const int bb = (m << 4) + ((lane >> 4) << 2);
#pragma unroll
                for (int r = 0; r < 4; ++r)
                    gl[w][bb + r][(n2 << 4) + rA] = acc[n2][m][r];
            }
        __syncthreads();

        // Fused gates: thread handles (b, cl=w*2+e); r-index = g*8+cl
#pragma unroll
        for (int e = 0; e < 2; ++e) {
            const int cl = (w << 1) + e;
            float gv[4];
#pragma unroll
            for (int g = 0; g < 4; ++g)
                gv[g] = gl[0][b][(g << 3) + cl] + gl[1][b][(g << 3) + cl]
                      + gl[2][b][(g << 3) + cl] + gl[3][b][(g << 3) + cl]
                      + brg[e][g] + xv[e][g];
            const float i_ = 1.f / (1.f + __expf(-gv[0]));
            const float f_ = 1.f / (1.f + __expf(-gv[1]));
            const float o_ = 1.f / (1.f + __expf(-gv[2]));
            const float ct = tanhf(gv[3]);
            const float cn = f_ * creg[e] + i_ * ct;
            creg[e] = cn;
            hs[b][cl] = o_ * tanhf(cn);
        }
        __syncthreads();

        // Gathered stores: one row per thread (tid<64): 32B out + 16B h bf16
        if (tid < 64) {
            float v[8];
#pragma unroll
            for (int k = 0; k < 8; ++k) v[k] = hs[tid][k];
            float* orow = out + (((size_t)s << 6) + tid) * 1024 + j0;
            *reinterpret_cast<float4*>(orow)     = make_float4(v[0], v[1], v[2], v[3]);
            *reinterpret_cast<float4*>(orow + 4) = make_float4(v[4], v[5], v[6], v[7]);
            union { __hip_bfloat16 bh[8]; sht8 sv; } u;
#pragma unroll
            for (int k = 0; k < 8; ++k) u.bh[k] = __float2bfloat16(v[k]);
            *reinterpret_cast<sht8*>(hn + ((size_t)tid << 10) + j0) = u.sv;
        }
        gbar_flags(flags, stepBase + (unsigned)(s + 1));

#pragma unroll
        for (int e = 0; e < 2; ++e)
#pragma unroll
            for (int g = 0; g < 4; ++g)
                xv[e][g] = xn[e][g];
    }

    // Persist c for next chunk / final epilogue
#pragma unroll
    for (int e = 0; e < 2; ++e)
        cbuf[(b << 10) + j0 + (w << 1) + e] = creg[e];
}

extern "C" void kernel_launch(void* const* d_in, const int* in_sizes, int n_in,
                              void* d_out, int out_size, void* d_ws, size_t ws_size,
                              hipStream_t stream)
{
    const float* inputs = (const float*)d_in[0];
    const float* H0     = (const float*)d_in[1];
    const float* C0     = (const float*)d_in[2];

    WP wp;
    wp.wx[0] = (const float*)d_in[3];  wp.bx[0] = (const float*)d_in[4];
    wp.wh[0] = (const float*)d_in[5];  wp.bh[0] = (const float*)d_in[6];
    wp.wx[1] = (const float*)d_in[7];  wp.bx[1] = (const float*)d_in[8];
    wp.wh[1] = (const float*)d_in[9];  wp.bh[1] = (const float*)d_in[10];
    wp.wx[2] = (const float*)d_in[11]; wp.bx[2] = (const float*)d_in[12];
    wp.wh[2] = (const float*)d_in[13]; wp.bh[2] = (const float*)d_in[14];
    wp.wx[3] = (const float*)d_in[15]; wp.bx[3] = (const float*)d_in[16];
    wp.wh[3] = (const float*)d_in[17]; wp.bh[3] = (const float*)d_in[18];

    char* ws = (char*)d_ws;
    size_t off = 0;
    auto alloc = [&](size_t bytes) {
        void* p = ws + off;
        off = (off + bytes + 255) & ~(size_t)255;
        return p;
    };
    __hip_bfloat16* Wx   = (__hip_bfloat16*)alloc((size_t)4 * HDIM * INDIM * 2);
    __hip_bfloat16* Wh   = (__hip_bfloat16*)alloc((size_t)4 * HDIM * HDIM * 2);
    float*          bias = (float*)alloc((size_t)4 * HDIM * 4);
    __hip_bfloat16* xb   = (__hip_bfloat16*)alloc((size_t)T_STEPS * BATCH * INDIM * 2);
    __hip_bfloat16* hb0  = (__hip_bfloat16*)alloc((size_t)BATCH * HDIM * 2);
    __hip_bfloat16* hb1  = (__hip_bfloat16*)alloc((size_t)BATCH * HDIM * 2);
    float*          cbuf = (float*)alloc((size_t)BATCH * HDIM * 4);
    unsigned*       flags= (unsigned*)alloc((size_t)NWG * 16 * 4);

    // xproj chunk buffer: 1 MB per timestep ([4H][B] f32). Pick largest chunk
    // (divisor of 512) that fits the remaining workspace.
    const size_t per_t = (size_t)4 * HDIM * BATCH * 4;
    int TC = 0;
    for (int tc : {512, 256, 128, 64, 32, 16})
        if (off + (size_t)tc * per_t <= ws_size) { TC = tc; break; }
    if (TC == 0) return;
    float* xp = (float*)alloc((size_t)TC * per_t);

    float* out = (float*)d_out;

    hipMemsetAsync(flags, 0, (size_t)NWG * 16 * 4, stream);  // deterministic replays
    hipLaunchKernelGGL(pack_weights, dim3(2048), dim3(256), 0, stream, wp, Wx, Wh, bias);
    hipLaunchKernelGGL(cast_f32_bf16, dim3(2048), dim3(256), 0, stream,
                       inputs, xb, T_STEPS * BATCH * INDIM / 4);
    hipLaunchKernelGGL(init_state, dim3(256), dim3(256), 0, stream, H0, C0, hb0, cbuf);

    unsigned stepBase = 0;
    for (int t0 = 0; t0 < T_STEPS; t0 += TC) {
        hipLaunchKernelGGL(xproj_gemm, dim3(TC, 32), dim3(256), 0, stream,
                           xb + (size_t)t0 * BATCH * INDIM, Wx, xp);
        hipLaunchKernelGGL(lstm_persist, dim3(NWG), dim3(256), 0, stream,
                           (const float*)xp, (const __hip_bfloat16*)Wh,
                           (const float*)bias, hb0, hb1, cbuf,
                           out + (size_t)t0 * BATCH * HDIM, flags, stepBase, TC);
        stepBase += (unsigned)TC;
    }
    hipLaunchKernelGGL(epilogue, dim3(256), dim3(256), 0, stream,
                       out + (size_t)(T_STEPS - 1) * BATCH * HDIM, cbuf,
                       out + (size_t)T_STEPS * BATCH * HDIM,
                       out + (size_t)T_STEPS * BATCH * HDIM + BATCH * HDIM);
}

// Round 6
// 6784.505 us; speedup vs baseline: 2.8587x; 1.3701x over previous
//
#include <hip/hip_runtime.h>
#include <hip/hip_bf16.h>
#include <math.h>

#define T_STEPS 512
#define BATCH   64
#define INDIM   1024
#define HDIM    1024
#define NWG     128      // persistent WGs; each owns 8 hidden cols

using bf16x8 = __attribute__((ext_vector_type(8))) __bf16;
using f32x4  = __attribute__((ext_vector_type(4))) float;
typedef unsigned long long u64;

struct WP {
    const float* wx[4];
    const float* wh[4];
    const float* bx[4];
    const float* bh[4];
};

// Pack 8 weight matrices into combined bf16 [4H][K] layouts + combined bias.
__global__ void pack_weights(WP p, __hip_bfloat16* __restrict__ Wx,
                             __hip_bfloat16* __restrict__ Wh, float* __restrict__ bias)
{
    int i = blockIdx.x * blockDim.x + threadIdx.x;
    const int stride = gridDim.x * blockDim.x;
    const int total = 4 * HDIM * INDIM;
    for (int idx = i; idx < total; idx += stride) {
        int g = idx >> 20;
        int r = idx & ((1 << 20) - 1);
        Wx[idx] = __float2bfloat16(p.wx[g][r]);
        Wh[idx] = __float2bfloat16(p.wh[g][r]);
    }
    if (i < 4 * HDIM) {
        int g = i >> 10, r = i & 1023;
        bias[i] = p.bx[g][r] + p.bh[g][r];
    }
}

__global__ void cast_f32_bf16(const float* __restrict__ in,
                              __hip_bfloat16* __restrict__ out, int n4)
{
    int i = blockIdx.x * blockDim.x + threadIdx.x;
    const int stride = gridDim.x * blockDim.x;
    for (; i < n4; i += stride) {
        float4 v = ((const float4*)in)[i];
        union { __hip_bfloat16 b[4]; short4 s; } u;
        u.b[0] = __float2bfloat16(v.x);
        u.b[1] = __float2bfloat16(v.y);
        u.b[2] = __float2bfloat16(v.z);
        u.b[3] = __float2bfloat16(v.w);
        ((short4*)out)[i] = u.s;
    }
}

__global__ void init_state(const float* __restrict__ H0, const float* __restrict__ C0,
                           __hip_bfloat16* __restrict__ h0, float* __restrict__ c)
{
    int i = blockIdx.x * blockDim.x + threadIdx.x;
    if (i < BATCH * HDIM) {
        h0[i] = __float2bfloat16(H0[i]);
        c[i]  = C0[i];
    }
}

__global__ void epilogue(const float* __restrict__ lasth, const float* __restrict__ c,
                         float* __restrict__ Hf, float* __restrict__ Cf)
{
    int i = blockIdx.x * blockDim.x + threadIdx.x;
    if (i < BATCH * HDIM) {
        Hf[i] = lasth[i];
        Cf[i] = c[i];
    }
}

// xproj GEMM: xp[t][n][b] = sum_k xb[t*64+b][k] * Wx[n][k]   (f32 out)
// Grid (TC, 32). Per WG: one t (M=64), N=128. 4 waves, each 2 n-tiles of 16.
__global__ __launch_bounds__(256, 2) void xproj_gemm(
    const __hip_bfloat16* __restrict__ xb,   // chunk base [TC*64][1024]
    const __hip_bfloat16* __restrict__ Wx,   // [4096][1024]
    float* __restrict__ xp)                  // [TC][4096][64]
{
    __shared__ float ct[4][64][33];
    const int t = blockIdx.x;
    const int n0 = blockIdx.y << 7;
    const int tid = threadIdx.x, w = tid >> 6, lane = tid & 63;
    const int rA = lane & 15, kg = (lane >> 4) << 3;
    const int nw = n0 + (w << 5);
    f32x4 acc[2][4] = {};
    const __hip_bfloat16* Arow = xb + (((size_t)t << 6) + rA) * 1024 + kg;
    const __hip_bfloat16* Brow = Wx + ((size_t)(nw + rA) << 10) + kg;
#pragma unroll 4
    for (int kk = 0; kk < 32; ++kk) {
        const int kb = kk << 5;
        bf16x8 bf0 = *reinterpret_cast<const bf16x8*>(Brow + kb);
        bf16x8 bf1 = *reinterpret_cast<const bf16x8*>(Brow + (16 << 10) + kb);
        bf16x8 af[4];
#pragma unroll
        for (int m = 0; m < 4; ++m)
            af[m] = *reinterpret_cast<const bf16x8*>(Arow + (m << 14) + kb);
#pragma unroll
        for (int m = 0; m < 4; ++m) {
            acc[0][m] = __builtin_amdgcn_mfma_f32_16x16x32_bf16(af[m], bf0, acc[0][m], 0, 0, 0);
            acc[1][m] = __builtin_amdgcn_mfma_f32_16x16x32_bf16(af[m], bf1, acc[1][m], 0, 0, 0);
        }
    }
#pragma unroll
    for (int n2 = 0; n2 < 2; ++n2)
#pragma unroll
        for (int m = 0; m < 4; ++m) {
            const int bb = (m << 4) + ((lane >> 4) << 2);
#pragma unroll
            for (int r = 0; r < 4; ++r)
                ct[w][bb + r][(n2 << 4) + rA] = acc[n2][m][r];
        }
    __syncthreads();
    const int n = lane & 31, mh = lane >> 5;
    float* obase = xp + ((size_t)t * 4096 + nw + n) * 64 + (mh << 5);
#pragma unroll
    for (int j = 0; j < 8; ++j) {
        const int m0 = (mh << 5) + (j << 2);
        *reinterpret_cast<float4*>(obase + (j << 2)) = make_float4(
            ct[w][m0 + 0][n], ct[w][m0 + 1][n], ct[w][m0 + 2][n], ct[w][m0 + 3][n]);
    }
}

// Fence-free global barrier. All shared data (h) moves via relaxed agent-scope
// atomics (L2-bypass, coherent at MALL). Ordering: __syncthreads drains
// vmcnt(0) -> h stores acked at MALL before flag store issues. No buffer_wbl2
// / buffer_inv anywhere. Bounded spin: on logic error we produce wrong output
// (visible bench failure) instead of wedging the GPU.
__device__ __forceinline__ void gbar_nofence(unsigned* flags, unsigned target)
{
    __syncthreads();                         // vmcnt(0): h atomics acked at MALL
    if (threadIdx.x == 0)
        __hip_atomic_store(&flags[(int)blockIdx.x * 16], target,
                           __ATOMIC_RELAXED, __HIP_MEMORY_SCOPE_AGENT);
    if (threadIdx.x < 64) {
        const unsigned* f0 = &flags[threadIdx.x * 16];
        const unsigned* f1 = &flags[(threadIdx.x + 64) * 16];
        int guard = 1 << 20;
        while ((__hip_atomic_load(f0, __ATOMIC_RELAXED, __HIP_MEMORY_SCOPE_AGENT) < target ||
                __hip_atomic_load(f1, __ATOMIC_RELAXED, __HIP_MEMORY_SCOPE_AGENT) < target)
               && --guard > 0)
            __builtin_amdgcn_s_sleep(1);
    }
    __syncthreads();
}

__device__ __forceinline__ float fast_sigmoid(float x)
{
    return 1.f / (1.f + __expf(-x));
}
__device__ __forceinline__ float fast_tanh(float x)
{
    x = fminf(15.f, fmaxf(-15.f, x));
    const float e = __expf(2.f * x);
    return (e - 1.f) / (e + 1.f);
}

// Persistent recurrence kernel. Grid = NWG(128) x 256 threads.
// WG wg owns hidden cols [wg*8, wg*8+8): 32 gate-rows, Wh slice in registers.
// h is exchanged through MALL via relaxed agent atomics (no fences).
__global__ __launch_bounds__(256, 1) void lstm_persist(
    const float* __restrict__ xp,            // [TC][4096][64]
    const __hip_bfloat16* __restrict__ Wh,   // [4096][1024]
    const float* __restrict__ bias,          // [4096]
    __hip_bfloat16* __restrict__ hA,         // state at chunk start
    __hip_bfloat16* __restrict__ hB,
    float* __restrict__ cbuf,                // [64][1024]
    float* __restrict__ out,                 // [TC][64][1024]
    unsigned* __restrict__ flags,            // [NWG*16] barrier flags
    unsigned stepBase,                       // steps completed in prior chunks
    int TC)
{
    __shared__ float gl[4][64][33];          // per-wave partials [w][b][r<32]
    __shared__ float hs[64][9];              // gathered h f32 (padded)

    const int tid  = threadIdx.x;
    const int w    = tid >> 6;
    const int lane = tid & 63;
    const int rA   = lane & 15;
    const int kg   = (lane >> 4) << 3;
    const int j0   = blockIdx.x << 3;

    // Preload this wave's Wh fragments (its K-quarter of 32 gate-rows).
    // gate-row r -> global row (r>>3)*1024 + j0 + (r&7)
    bf16x8 whf[2][8];
#pragma unroll
    for (int n2 = 0; n2 < 2; ++n2) {
        const int row  = (n2 << 4) + rA;
        const int grow = ((row >> 3) << 10) + j0 + (row & 7);
        const __hip_bfloat16* wr = Wh + ((size_t)grow << 10) + (w << 8) + kg;
#pragma unroll
        for (int kk = 0; kk < 8; ++kk)
            whf[n2][kk] = *reinterpret_cast<const bf16x8*>(wr + (kk << 5));
    }

    // Gate-phase persistent state: thread (b=lane, cols cl=w*2+{0,1})
    const int b = lane;
    float creg[2], brg[2][4];
#pragma unroll
    for (int e = 0; e < 2; ++e) {
        const int cl = (w << 1) + e;
        creg[e] = cbuf[(b << 10) + j0 + cl];
#pragma unroll
        for (int g = 0; g < 4; ++g) brg[e][g] = bias[(g << 10) + j0 + cl];
    }

#define LOAD_XV(dst, sidx)                                                     \
    do {                                                                       \
        const float* xpt_ = xp + (size_t)(sidx) * 262144;                      \
        _Pragma("unroll") for (int e = 0; e < 2; ++e)                          \
        _Pragma("unroll") for (int g = 0; g < 4; ++g)                          \
            dst[e][g] = xpt_[(((g << 10) + j0 + (w << 1) + e) << 6) + b];      \
    } while (0)

    float xv[2][4];
    LOAD_XV(xv, 0);

    for (int s = 0; s < TC; ++s) {
        const __hip_bfloat16* hp = (s & 1) ? hB : hA;
        __hip_bfloat16*       hn = (s & 1) ? hA : hB;

        // Prefetch next step's xproj early; latency hides under GEMM+gates+barrier.
        float xn[2][4];
        if (s + 1 < TC) LOAD_XV(xn, s + 1);

        // h-GEMM over this wave's K-quarter. h loads are relaxed agent-scope
        // 8B atomics (L2-bypass -> MALL), staged in two register phases so
        // loads issue back-to-back and latency amortizes.
        f32x4 acc[2][4] = {};
        const __hip_bfloat16* hbase = hp + (w << 8) + kg;
#pragma unroll
        for (int hhalf = 0; hhalf < 2; ++hhalf) {
            u64 aq[4][4][2];
#pragma unroll
            for (int k2 = 0; k2 < 4; ++k2) {
                const int kk = (hhalf << 2) + k2;
#pragma unroll
                for (int m = 0; m < 4; ++m) {
                    const u64* p = (const u64*)(hbase + (((m << 4) + rA) << 10) + (kk << 5));
                    aq[k2][m][0] = __hip_atomic_load(p,     __ATOMIC_RELAXED, __HIP_MEMORY_SCOPE_AGENT);
                    aq[k2][m][1] = __hip_atomic_load(p + 1, __ATOMIC_RELAXED, __HIP_MEMORY_SCOPE_AGENT);
                }
            }
#pragma unroll
            for (int k2 = 0; k2 < 4; ++k2) {
                const int kk = (hhalf << 2) + k2;
#pragma unroll
                for (int m = 0; m < 4; ++m) {
                    union { u64 q[2]; bf16x8 v; } c;
                    c.q[0] = aq[k2][m][0];
                    c.q[1] = aq[k2][m][1];
#pragma unroll
                    for (int n2 = 0; n2 < 2; ++n2)
                        acc[n2][m] = __builtin_amdgcn_mfma_f32_16x16x32_bf16(
                            c.v, whf[n2][kk], acc[n2][m], 0, 0, 0);
                }
            }
        }

        // Write partials: C/D layout col=lane&15, row=(lane>>4)*4+r
#pragma unroll
        for (int n2 = 0; n2 < 2; ++n2)
#pragma unroll
            for (int m = 0; m < 4; ++m) {
                const int bb = (m << 4) + ((lane >> 4) << 2);
#pragma unroll
                for (int r = 0; r < 4; ++r)
                    gl[w][bb + r][(n2 << 4) + rA] = acc[n2][m][r];
            }
        __syncthreads();

        // Fused gates: thread handles (b, cl=w*2+e); r-index = g*8+cl
#pragma unroll
        for (int e = 0; e < 2; ++e) {
            const int cl = (w << 1) + e;
            float gv[4];
#pragma unroll
            for (int g = 0; g < 4; ++g)
                gv[g] = gl[0][b][(g << 3) + cl] + gl[1][b][(g << 3) + cl]
                      + gl[2][b][(g << 3) + cl] + gl[3][b][(g << 3) + cl]
                      + brg[e][g] + xv[e][g];
            const float i_ = fast_sigmoid(gv[0]);
            const float f_ = fast_sigmoid(gv[1]);
            const float o_ = fast_sigmoid(gv[2]);
            const float ct = fast_tanh(gv[3]);
            const float cn = f_ * creg[e] + i_ * ct;
            creg[e] = cn;
            hs[b][cl] = o_ * fast_tanh(cn);
        }
        __syncthreads();

        // Gathered stores: one row per thread (tid<64). out: plain (private).
        // h: relaxed agent atomics (write-through to MALL).
        if (tid < 64) {
            float v[8];
#pragma unroll
            for (int k = 0; k < 8; ++k) v[k] = hs[tid][k];
            float* orow = out + (((size_t)s << 6) + tid) * 1024 + j0;
            *reinterpret_cast<float4*>(orow)     = make_float4(v[0], v[1], v[2], v[3]);
            *reinterpret_cast<float4*>(orow + 4) = make_float4(v[4], v[5], v[6], v[7]);
            union { __hip_bfloat16 bh[8]; u64 q[2]; } u;
#pragma unroll
            for (int k = 0; k < 8; ++k) u.bh[k] = __float2bfloat16(v[k]);
            u64* hq = (u64*)(hn + ((size_t)tid << 10) + j0);
            __hip_atomic_store(hq,     u.q[0], __ATOMIC_RELAXED, __HIP_MEMORY_SCOPE_AGENT);
            __hip_atomic_store(hq + 1, u.q[1], __ATOMIC_RELAXED, __HIP_MEMORY_SCOPE_AGENT);
        }
        gbar_nofence(flags, stepBase + (unsigned)(s + 1));

#pragma unroll
        for (int e = 0; e < 2; ++e)
#pragma unroll
            for (int g = 0; g < 4; ++g)
                xv[e][g] = xn[e][g];
    }

    // Persist c for next chunk / final epilogue (kernel-end release handles it)
#pragma unroll
    for (int e = 0; e < 2; ++e)
        cbuf[(b << 10) + j0 + (w << 1) + e] = creg[e];
}

extern "C" void kernel_launch(void* const* d_in, const int* in_sizes, int n_in,
                              void* d_out, int out_size, void* d_ws, size_t ws_size,
                              hipStream_t stream)
{
    const float* inputs = (const float*)d_in[0];
    const float* H0     = (const float*)d_in[1];
    const float* C0     = (const float*)d_in[2];

    WP wp;
    wp.wx[0] = (const float*)d_in[3];  wp.bx[0] = (const float*)d_in[4];
    wp.wh[0] = (const float*)d_in[5];  wp.bh[0] = (const float*)d_in[6];
    wp.wx[1] = (const float*)d_in[7];  wp.bx[1] = (const float*)d_in[8];
    wp.wh[1] = (const float*)d_in[9];  wp.bh[1] = (const float*)d_in[10];
    wp.wx[2] = (const float*)d_in[11]; wp.bx[2] = (const float*)d_in[12];
    wp.wh[2] = (const float*)d_in[13]; wp.bh[2] = (const float*)d_in[14];
    wp.wx[3] = (const float*)d_in[15]; wp.bx[3] = (const float*)d_in[16];
    wp.wh[3] = (const float*)d_in[17]; wp.bh[3] = (const float*)d_in[18];

    char* ws = (char*)d_ws;
    size_t off = 0;
    auto alloc = [&](size_t bytes) {
        void* p = ws + off;
        off = (off + bytes + 255) & ~(size_t)255;
        return p;
    };
    __hip_bfloat16* Wx   = (__hip_bfloat16*)alloc((size_t)4 * HDIM * INDIM * 2);
    __hip_bfloat16* Wh   = (__hip_bfloat16*)alloc((size_t)4 * HDIM * HDIM * 2);
    float*          bias = (float*)alloc((size_t)4 * HDIM * 4);
    __hip_bfloat16* xb   = (__hip_bfloat16*)alloc((size_t)T_STEPS * BATCH * INDIM * 2);
    __hip_bfloat16* hb0  = (__hip_bfloat16*)alloc((size_t)BATCH * HDIM * 2);
    __hip_bfloat16* hb1  = (__hip_bfloat16*)alloc((size_t)BATCH * HDIM * 2);
    float*          cbuf = (float*)alloc((size_t)BATCH * HDIM * 4);
    unsigned*       flags= (unsigned*)alloc((size_t)NWG * 16 * 4);

    // xproj chunk buffer: 1 MB per timestep ([4H][B] f32). Pick largest chunk
    // (divisor of 512) that fits the remaining workspace.
    const size_t per_t = (size_t)4 * HDIM * BATCH * 4;
    int TC = 0;
    for (int tc : {512, 256, 128, 64, 32, 16})
        if (off + (size_t)tc * per_t <= ws_size) { TC = tc; break; }
    if (TC == 0) return;
    float* xp = (float*)alloc((size_t)TC * per_t);

    float* out = (float*)d_out;

    hipMemsetAsync(flags, 0, (size_t)NWG * 16 * 4, stream);  // deterministic replays
    hipLaunchKernelGGL(pack_weights, dim3(2048), dim3(256), 0, stream, wp, Wx, Wh, bias);
    hipLaunchKernelGGL(cast_f32_bf16, dim3(2048), dim3(256), 0, stream,
                       inputs, xb, T_STEPS * BATCH * INDIM / 4);
    hipLaunchKernelGGL(init_state, dim3(256), dim3(256), 0, stream, H0, C0, hb0, cbuf);

    unsigned stepBase = 0;
    for (int t0 = 0; t0 < T_STEPS; t0 += TC) {
        hipLaunchKernelGGL(xproj_gemm, dim3(TC, 32), dim3(256), 0, stream,
                           xb + (size_t)t0 * BATCH * INDIM, Wx, xp);
        hipLaunchKernelGGL(lstm_persist, dim3(NWG), dim3(256), 0, stream,
                           (const float*)xp, (const __hip_bfloat16*)Wh,
                           (const float*)bias, hb0, hb1, cbuf,
                           out + (size_t)t0 * BATCH * HDIM, flags, stepBase, TC);
        stepBase += (unsigned)TC;
    }
    hipLaunchKernelGGL(epilogue, dim3(256), dim3(256), 0, stream,
                       out + (size_t)(T_STEPS - 1) * BATCH * HDIM, cbuf,
                       out + (size_t)T_STEPS * BATCH * HDIM,
                       out + (size_t)T_STEPS * BATCH * HDIM + BATCH * HDIM);
}